// Round 3
// baseline (455.716 us; speedup 1.0000x reference)
//
#include <hip/hip_runtime.h>
#include <stdint.h>

#define TOKENS 16384
#define DDIM   1024
#define NEXP   64
#define NCOL   128              // 64 gate + 64 noise cols
#define MT     64               // tokens per GEMM block
#define KB     16               // k-tile (16.6 KB LDS)
#define KSPLIT 8
#define KCH    (DDIM / KSPLIT)  // 128 k per block
#define NTT    (TOKENS / MT)    // 256 token tiles

// -------- device-global scratch --------
__device__ float g_part[KSPLIT][TOKENS][NCOL];  // 67 MB split-K partials
__device__ float g_ps[NEXP];                    // sum of clean router probs per expert
__device__ float g_cnt[NEXP];                   // top-2 counts per expert
__device__ float g_spa[1];                      // sum of softplus
__device__ unsigned g_done;                     // K2 completion counter (zero-init)

// ---------------- JAX threefry2x32 (20 rounds) ----------------
struct U2 { uint32_t a, b; };

__host__ __device__ constexpr U2 tf2x32(uint32_t k0, uint32_t k1,
                                        uint32_t x0, uint32_t x1) {
  uint32_t ks[3] = {k0, k1, k0 ^ k1 ^ 0x1BD11BDAu};
  const uint32_t rot[2][4] = {{13u, 15u, 26u, 6u}, {17u, 29u, 16u, 24u}};
  x0 += ks[0]; x1 += ks[1];
  for (int d = 0; d < 5; ++d) {
    for (int j = 0; j < 4; ++j) {
      uint32_t r = rot[d & 1][j];
      x0 += x1;
      x1 = (x1 << r) | (x1 >> (32u - r));
      x1 ^= x0;
    }
    x0 += ks[(d + 1) % 3];
    x1 += ks[(d + 2) % 3] + (uint32_t)(d + 1);
  }
  return U2{x0, x1};
}

// JAX >=0.5 partitionable threefry: bits[i] = xor-fold(tf(key, (0, i)))
__device__ inline uint32_t noise_bits(uint32_t i) {
  constexpr U2 NK = tf2x32(0u, 0u, 0u, 12345u);   // fold_in(key(0), 12345)
  U2 o = tf2x32(NK.a, NK.b, 0u, i);
  return o.a ^ o.b;
}

// XLA ErfInv32 (Giles polynomial)
__device__ inline float xla_erfinv(float x) {
  float w = -log1pf(-x * x);
  float p;
  if (w < 5.0f) {
    w = w - 2.5f;
    p = 2.81022636e-08f;
    p = 3.43273939e-07f + p * w;
    p = -3.5233877e-06f + p * w;
    p = -4.39150654e-06f + p * w;
    p = 0.00021858087f + p * w;
    p = -0.00125372503f + p * w;
    p = -0.00417768164f + p * w;
    p = 0.246640727f + p * w;
    p = 1.50140941f + p * w;
  } else {
    w = sqrtf(w) - 3.0f;
    p = -0.000200214257f;
    p = 0.000100950558f + p * w;
    p = 0.00134934322f + p * w;
    p = -0.00367342844f + p * w;
    p = 0.00573950773f + p * w;
    p = -0.0076224613f + p * w;
    p = 0.00943887047f + p * w;
    p = 1.00167406f + p * w;
    p = 2.83297682f + p * w;
  }
  return p * x;
}

__device__ inline float noise_normal(uint32_t i) {
  uint32_t bits = noise_bits(i);
  float f = __uint_as_float((bits >> 9) | 0x3f800000u) - 1.0f;  // [0,1)
  float u = f * 2.0f + (-0.99999994f);
  u = fmaxf(u, -0.99999994f);
  return 1.41421356237f * xla_erfinv(u);
}

__device__ inline float softplus_ref(float x) {
  return fmaxf(x, 0.0f) + log1pf(expf(-fabsf(x)));
}

// ---------------- wave(64) primitives ----------------
__device__ inline float wave_max64(float v) {
  #pragma unroll
  for (int off = 32; off; off >>= 1) v = fmaxf(v, __shfl_xor(v, off, 64));
  return v;
}
__device__ inline float wave_sum64(float v) {
  #pragma unroll
  for (int off = 32; off; off >>= 1) v += __shfl_xor(v, off, 64);
  return v;
}
__device__ inline void wave_argmax64(float v, int idx, float& mv, int& mi) {
  float bv = v; int bi = idx;
  #pragma unroll
  for (int off = 32; off; off >>= 1) {
    float ov = __shfl_xor(bv, off, 64);
    int   oi = __shfl_xor(bi, off, 64);
    if (ov > bv || (ov == bv && oi < bi)) { bv = ov; bi = oi; }
  }
  mv = bv; mi = bi;
}

// ---------------- K1: split-K GEMM with register prefetch ----------------
// block = 64 tokens x 128 cols x 128 k; grid = (256 token-tiles, 8 k-splits)
// Tile kt+1 is loaded into registers BEFORE the FMA block of tile kt so the
// global-load latency hides under the ~2048-cycle compute. Arithmetic order
// identical to round 1 (absmax-safe).
__global__ __launch_bounds__(128, 4)
void NoisyTopKRouter_57621281243491_kernel(
    const float* __restrict__ x, const float* __restrict__ wg,
    const float* __restrict__ wn) {
  // zero loss accumulators (kernel-boundary ordering vs epilogue)
  if (blockIdx.x == 0 && blockIdx.y == 0) {
    if (threadIdx.x < NEXP) { g_ps[threadIdx.x] = 0.0f; g_cnt[threadIdx.x] = 0.0f; }
    if (threadIdx.x == NEXP) g_spa[0] = 0.0f;
  }

  __shared__ float xs[KB][MT + 4];   // x^T tile: xs[k][token]   4.35 KB
  __shared__ float wsd[KB][192];     // W^T tile: wsd[k][wcol]  12.29 KB

  const int tid = threadIdx.x;
  const int tx = tid & 15;    // col group: cols tx*8..+7
  const int ty = tid >> 4;    // token group: tokens ty*8..+7 (0..7)
  const int tok0 = blockIdx.x * MT;
  const int k0   = blockIdx.y * KCH;

  const int stok = tid >> 1;         // 0..63: x staging token
  const int skb  = (tid & 1) * 8;    // x staging k offset (0 or 8)
  const int wcl  = tid;              // 0..127: W staging col
  const float* wrow = (wcl < NEXP) ? (wg + (size_t)wcl * DDIM)
                                   : (wn + (size_t)(wcl - NEXP) * DDIM);
  const int wc = wcl + ((wcl >> 3) << 2);   // interleaved col: 2-way banks (free)

  const float* xrow = x + (size_t)(tok0 + stok) * DDIM + skb;

  float acc[8][8] = {};
  float4 xv[2], wv[4];

  {  // prologue: load tile 0
    #pragma unroll
    for (int it = 0; it < 2; ++it) xv[it] = *(const float4*)&xrow[k0 + it * 4];
    #pragma unroll
    for (int it = 0; it < 4; ++it) wv[it] = *(const float4*)&wrow[k0 + it * 4];
  }

  for (int kt = 0; kt < KCH / KB; ++kt) {   // 8 k-tiles of 16
    if (kt) __syncthreads();           // previous tile's LDS readers done
    #pragma unroll
    for (int it = 0; it < 2; ++it) {
      const int kb = skb + it * 4;
      xs[kb + 0][stok] = xv[it].x; xs[kb + 1][stok] = xv[it].y;
      xs[kb + 2][stok] = xv[it].z; xs[kb + 3][stok] = xv[it].w;
    }
    #pragma unroll
    for (int it = 0; it < 4; ++it) {
      const int kb = it * 4;
      wsd[kb + 0][wc] = wv[it].x; wsd[kb + 1][wc] = wv[it].y;
      wsd[kb + 2][wc] = wv[it].z; wsd[kb + 3][wc] = wv[it].w;
    }
    __syncthreads();

    // prefetch next tile while computing this one
    if (kt < KCH / KB - 1) {
      const int kk0 = k0 + (kt + 1) * KB;
      #pragma unroll
      for (int it = 0; it < 2; ++it) xv[it] = *(const float4*)&xrow[kk0 + it * 4];
      #pragma unroll
      for (int it = 0; it < 4; ++it) wv[it] = *(const float4*)&wrow[kk0 + it * 4];
    }

    #pragma unroll
    for (int kk = 0; kk < KB; ++kk) {
      const float4 a0 = *(const float4*)&xs[kk][ty * 8];        // 16-lane broadcast
      const float4 a1 = *(const float4*)&xs[kk][ty * 8 + 4];
      const float4 b0 = *(const float4*)&wsd[kk][tx * 12];      // 2-way banks
      const float4 b1 = *(const float4*)&wsd[kk][tx * 12 + 4];
      const float av[8] = {a0.x, a0.y, a0.z, a0.w, a1.x, a1.y, a1.z, a1.w};
      const float bv[8] = {b0.x, b0.y, b0.z, b0.w, b1.x, b1.y, b1.z, b1.w};
      #pragma unroll
      for (int i = 0; i < 8; ++i)
        #pragma unroll
        for (int j = 0; j < 8; ++j)
          acc[i][j] += av[i] * bv[j];
    }
  }

  // write split-K partials (coalesced float4, plain column layout)
  float* dst = &g_part[blockIdx.y][0][0];
  #pragma unroll
  for (int i = 0; i < 8; ++i) {
    const size_t t = (size_t)(tok0 + ty * 8 + i);
    *(float4*)&dst[t * NCOL + tx * 8]     = make_float4(acc[i][0], acc[i][1], acc[i][2], acc[i][3]);
    *(float4*)&dst[t * NCOL + tx * 8 + 4] = make_float4(acc[i][4], acc[i][5], acc[i][6], acc[i][7]);
  }
}

// ---------------- K2: combine partials + router epilogue + finalize ----------------
// grid = 1024 blocks x 1024 threads; one token per wave (16 waves/block).
// Last block to finish (device-scope done-counter) finalizes the scalars —
// no grid barrier, no co-residency assumption, deadlock-free.
__global__ __launch_bounds__(1024)
void epilogue_kernel(float* __restrict__ out) {
  const int tid  = threadIdx.x;
  const int lane = tid & 63;
  const int w    = tid >> 6;    // 0..15
  const int t    = blockIdx.x * 16 + w;

  float* out_rw  = out;                        // [16384][2]
  float* out_idx = out + 2 * TOKENS;           // [16384][2]
  float* out_rp  = out + 4 * TOKENS + 1;       // [16384][64]

  // combine split-K partials (16 independent loads, latency hidden by occupancy)
  float cl = 0.0f, nl = 0.0f;
  #pragma unroll
  for (int s = 0; s < KSPLIT; ++s) {
    cl += g_part[s][t][lane];
    nl += g_part[s][t][NEXP + lane];
  }

  // router_probs = softmax(clean)
  const float m  = wave_max64(cl);
  const float v  = expf(cl - m);
  const float Z  = wave_sum64(v);
  const float rp = v / Z;
  out_rp[(size_t)t * NEXP + lane] = rp;

  // noisy logits
  const float ns  = softplus_ref(nl);
  const float noi = noise_normal((uint32_t)(t * NEXP + lane));
  const float lgn = __fadd_rn(cl, __fmul_rn(noi, ns));

  const float m2 = wave_max64(lgn);
  const float v2 = expf(lgn - m2);
  const float Z2 = wave_sum64(v2);
  const float p  = v2 / Z2;

  float p1; int i1;
  wave_argmax64(p, lane, p1, i1);
  const float pm = (lane == i1) ? -3.402823466e38f : p;
  float p2; int i2;
  wave_argmax64(pm, lane, p2, i2);

  const float c_acc = (float)((lane == i1) + (lane == i2));

  if (lane == 0) {
    const float s = p1 + p2;
    out_rw[t * 2 + 0]  = p1 / s;
    out_rw[t * 2 + 1]  = p2 / s;
    out_idx[t * 2 + 0] = (float)i1;
    out_idx[t * 2 + 1] = (float)i2;
  }

  // block-level reduce, then one atomicAdd set per block
  __shared__ float lps[16][NEXP];
  __shared__ float lcb[16][NEXP];
  __shared__ float lspw[16];
  lps[w][lane] = rp;
  lcb[w][lane] = c_acc;
  const float spw = wave_sum64(ns);
  if (lane == 0) lspw[w] = spw;
  __syncthreads();
  if (tid < NEXP) {
    float a = 0.0f, b = 0.0f;
    #pragma unroll
    for (int j = 0; j < 16; ++j) { a += lps[j][tid]; b += lcb[j][tid]; }
    atomicAdd(&g_ps[tid],  a);
    atomicAdd(&g_cnt[tid], b);
  }
  if (tid == 0) {
    float s = 0.0f;
    #pragma unroll
    for (int j = 0; j < 16; ++j) s += lspw[j];
    atomicAdd(&g_spa[0], s);
  }

  // ---- last-done block finalizes scalars ----
  __syncthreads();             // all this block's atomics issued & drained
  __shared__ int s_last;
  if (tid == 0) {
    __threadfence();           // release our accumulator adds device-wide
    const unsigned prev = __hip_atomic_fetch_add(&g_done, 1u, __ATOMIC_ACQ_REL,
                                                 __HIP_MEMORY_SCOPE_AGENT);
    s_last = (prev == (unsigned)(gridDim.x - 1)) ? 1 : 0;
  }
  __syncthreads();
  if (s_last && tid < NEXP) {
    __threadfence();           // acquire side
    const float cnt = __hip_atomic_load(&g_cnt[tid], __ATOMIC_RELAXED, __HIP_MEMORY_SCOPE_AGENT);
    const float ps  = __hip_atomic_load(&g_ps[tid],  __ATOMIC_RELAXED, __HIP_MEMORY_SCOPE_AGENT);
    float term = (cnt / (float)TOKENS) * (ps / (float)TOKENS);
    #pragma unroll
    for (int off = 32; off; off >>= 1) term += __shfl_xor(term, off, 64);
    if (tid == 0) {
      out[4 * TOKENS] = 0.64f * term;   // LOAD_BALANCE_WEIGHT * NUM_EXPERTS
      const float spa = __hip_atomic_load(&g_spa[0], __ATOMIC_RELAXED, __HIP_MEMORY_SCOPE_AGENT);
      out[4 * TOKENS + 1 + TOKENS * NEXP] = spa / (float)(TOKENS * NEXP);
      __hip_atomic_store(&g_done, 0u, __ATOMIC_RELAXED, __HIP_MEMORY_SCOPE_AGENT);
    }
  }
}

// ---------------- host ----------------
extern "C" void kernel_launch(void* const* d_in, const int* in_sizes, int n_in,
                              void* d_out, int out_size, void* d_ws, size_t ws_size,
                              hipStream_t stream) {
  const float* x  = (const float*)d_in[0];   // f32 [4,4096,1024]
  const float* wg = (const float*)d_in[1];   // f32 [64,1024]
  const float* wn = (const float*)d_in[2];   // f32 [64,1024]
  float* out = (float*)d_out;                // f32, 1114114 elements

  (void)d_ws; (void)ws_size; (void)in_sizes; (void)n_in; (void)out_size;

  NoisyTopKRouter_57621281243491_kernel<<<dim3(NTT, KSPLIT), 128, 0, stream>>>(x, wg, wn);
  epilogue_kernel<<<TOKENS / 16, 1024, 0, stream>>>(out);
}

// Round 4
// 233.131 us; speedup vs baseline: 1.9548x; 1.9548x over previous
//
#include <hip/hip_runtime.h>
#include <stdint.h>

#define TOKENS 16384
#define DDIM   1024
#define NEXP   64
#define NCOL   128              // 64 gate + 64 noise cols
#define MT     128              // tokens per GEMM block (128x128 output tile)
#define KB     16               // k-tile
#define KSPLIT 8
#define KCH    (DDIM / KSPLIT)  // 128 k per block
#define NTT    (TOKENS / MT)    // 128 token tiles

// -------- device-global scratch --------
__device__ float g_part[KSPLIT][TOKENS][NCOL];  // 67 MB split-K partials
__device__ float g_ps[NEXP];                    // sum of clean router probs per expert
__device__ float g_cnt[NEXP];                   // top-2 counts per expert
__device__ float g_spa[1];                      // sum of softplus
__device__ unsigned g_done;                     // K2 completion counter (zero-init)

// ---------------- JAX threefry2x32 (20 rounds) ----------------
struct U2 { uint32_t a, b; };

__host__ __device__ constexpr U2 tf2x32(uint32_t k0, uint32_t k1,
                                        uint32_t x0, uint32_t x1) {
  uint32_t ks[3] = {k0, k1, k0 ^ k1 ^ 0x1BD11BDAu};
  const uint32_t rot[2][4] = {{13u, 15u, 26u, 6u}, {17u, 29u, 16u, 24u}};
  x0 += ks[0]; x1 += ks[1];
  for (int d = 0; d < 5; ++d) {
    for (int j = 0; j < 4; ++j) {
      uint32_t r = rot[d & 1][j];
      x0 += x1;
      x1 = (x1 << r) | (x1 >> (32u - r));
      x1 ^= x0;
    }
    x0 += ks[(d + 1) % 3];
    x1 += ks[(d + 2) % 3] + (uint32_t)(d + 1);
  }
  return U2{x0, x1};
}

// JAX >=0.5 partitionable threefry: bits[i] = xor-fold(tf(key, (0, i)))
__device__ inline uint32_t noise_bits(uint32_t i) {
  constexpr U2 NK = tf2x32(0u, 0u, 0u, 12345u);   // fold_in(key(0), 12345)
  U2 o = tf2x32(NK.a, NK.b, 0u, i);
  return o.a ^ o.b;
}

// XLA ErfInv32 (Giles polynomial)
__device__ inline float xla_erfinv(float x) {
  float w = -log1pf(-x * x);
  float p;
  if (w < 5.0f) {
    w = w - 2.5f;
    p = 2.81022636e-08f;
    p = 3.43273939e-07f + p * w;
    p = -3.5233877e-06f + p * w;
    p = -4.39150654e-06f + p * w;
    p = 0.00021858087f + p * w;
    p = -0.00125372503f + p * w;
    p = -0.00417768164f + p * w;
    p = 0.246640727f + p * w;
    p = 1.50140941f + p * w;
  } else {
    w = sqrtf(w) - 3.0f;
    p = -0.000200214257f;
    p = 0.000100950558f + p * w;
    p = 0.00134934322f + p * w;
    p = -0.00367342844f + p * w;
    p = 0.00573950773f + p * w;
    p = -0.0076224613f + p * w;
    p = 0.00943887047f + p * w;
    p = 1.00167406f + p * w;
    p = 2.83297682f + p * w;
  }
  return p * x;
}

__device__ inline float noise_normal(uint32_t i) {
  uint32_t bits = noise_bits(i);
  float f = __uint_as_float((bits >> 9) | 0x3f800000u) - 1.0f;  // [0,1)
  float u = f * 2.0f + (-0.99999994f);
  u = fmaxf(u, -0.99999994f);
  return 1.41421356237f * xla_erfinv(u);
}

__device__ inline float softplus_ref(float x) {
  return fmaxf(x, 0.0f) + log1pf(expf(-fabsf(x)));
}

// ---------------- wave(64) primitives ----------------
__device__ inline float wave_max64(float v) {
  #pragma unroll
  for (int off = 32; off; off >>= 1) v = fmaxf(v, __shfl_xor(v, off, 64));
  return v;
}
__device__ inline float wave_sum64(float v) {
  #pragma unroll
  for (int off = 32; off; off >>= 1) v += __shfl_xor(v, off, 64);
  return v;
}
__device__ inline void wave_argmax64(float v, int idx, float& mv, int& mi) {
  float bv = v; int bi = idx;
  #pragma unroll
  for (int off = 32; off; off >>= 1) {
    float ov = __shfl_xor(bv, off, 64);
    int   oi = __shfl_xor(bi, off, 64);
    if (ov > bv || (ov == bv && oi < bi)) { bv = ov; bi = oi; }
  }
  mv = bv; mi = bi;
}

// ---------------- K1: split-K GEMM, 128x128 tile, 256 threads ----------------
// block = 128 tokens x 128 cols x 128 k; grid = (128 token-tiles, 8 k-splits)
// Round-1 staging structure (stage -> sync -> compute -> sync): no registers
// live across the FMA block (round-3's prefetch spilled to scratch, 4x slower).
// MT=128 halves W-staging traffic per token and halves barriers per CU.
// K-summation order per output unchanged -> bit-identical results.
__global__ __launch_bounds__(256, 4)
void NoisyTopKRouter_57621281243491_kernel(
    const float* __restrict__ x, const float* __restrict__ wg,
    const float* __restrict__ wn) {
  // zero loss accumulators (kernel-boundary ordering vs epilogue)
  if (blockIdx.x == 0 && blockIdx.y == 0) {
    if (threadIdx.x < NEXP) { g_ps[threadIdx.x] = 0.0f; g_cnt[threadIdx.x] = 0.0f; }
    if (threadIdx.x == NEXP) g_spa[0] = 0.0f;
  }

  __shared__ float xs[KB][MT + 4];   // x^T tile: xs[k][token]  [16][132] = 8.45 KB
  __shared__ float wsd[KB][192];     // W^T tile: wsd[k][wcol]  [16][192] = 12.3 KB

  const int tid = threadIdx.x;
  const int tx = tid & 15;    // col group: cols tx*8..+7
  const int ty = tid >> 4;    // token group: tokens ty*8..+7 (0..15)
  const int tok0 = blockIdx.x * MT;
  const int k0   = blockIdx.y * KCH;

  const int stok = tid >> 1;         // 0..127: x staging token
  const int skb  = (tid & 1) * 8;    // x staging k offset (0 or 8)
  const int wcl  = tid & 127;        // W staging col
  const int wkb  = (tid >> 7) * 8;   // W staging k offset (0 or 8)
  const float* wrow = (wcl < NEXP) ? (wg + (size_t)wcl * DDIM)
                                   : (wn + (size_t)(wcl - NEXP) * DDIM);
  const int wc = wcl + ((wcl >> 3) << 2);   // interleaved col: 2-way banks (free)

  const float* xrow = x + (size_t)(tok0 + stok) * DDIM + skb;

  float acc[8][8] = {};

  for (int kt = 0; kt < KCH / KB; ++kt) {   // 8 k-tiles of 16
    const int kk0 = k0 + kt * KB;

    float4 xv[2], wv[2];
    #pragma unroll
    for (int it = 0; it < 2; ++it)
      xv[it] = *(const float4*)&xrow[kk0 + it * 4];
    #pragma unroll
    for (int it = 0; it < 2; ++it)
      wv[it] = *(const float4*)&wrow[kk0 + wkb + it * 4];

    #pragma unroll
    for (int it = 0; it < 2; ++it) {
      const int kb = skb + it * 4;
      xs[kb + 0][stok] = xv[it].x; xs[kb + 1][stok] = xv[it].y;
      xs[kb + 2][stok] = xv[it].z; xs[kb + 3][stok] = xv[it].w;
    }
    #pragma unroll
    for (int it = 0; it < 2; ++it) {
      const int kb = wkb + it * 4;
      wsd[kb + 0][wc] = wv[it].x; wsd[kb + 1][wc] = wv[it].y;
      wsd[kb + 2][wc] = wv[it].z; wsd[kb + 3][wc] = wv[it].w;
    }
    __syncthreads();

    #pragma unroll
    for (int kk = 0; kk < KB; ++kk) {
      const float4 a0 = *(const float4*)&xs[kk][ty * 8];        // 4-addr broadcast
      const float4 a1 = *(const float4*)&xs[kk][ty * 8 + 4];
      const float4 b0 = *(const float4*)&wsd[kk][tx * 12];      // 2-way banks
      const float4 b1 = *(const float4*)&wsd[kk][tx * 12 + 4];
      const float av[8] = {a0.x, a0.y, a0.z, a0.w, a1.x, a1.y, a1.z, a1.w};
      const float bv[8] = {b0.x, b0.y, b0.z, b0.w, b1.x, b1.y, b1.z, b1.w};
      #pragma unroll
      for (int i = 0; i < 8; ++i)
        #pragma unroll
        for (int j = 0; j < 8; ++j)
          acc[i][j] += av[i] * bv[j];
    }
    __syncthreads();
  }

  // write split-K partials (coalesced float4, plain column layout)
  float* dst = &g_part[blockIdx.y][0][0];
  #pragma unroll
  for (int i = 0; i < 8; ++i) {
    const size_t t = (size_t)(tok0 + ty * 8 + i);
    *(float4*)&dst[t * NCOL + tx * 8]     = make_float4(acc[i][0], acc[i][1], acc[i][2], acc[i][3]);
    *(float4*)&dst[t * NCOL + tx * 8 + 4] = make_float4(acc[i][4], acc[i][5], acc[i][6], acc[i][7]);
  }
}

// ---------------- K2: combine partials + router epilogue + finalize ----------------
// grid = 1024 blocks x 1024 threads; one token per wave (16 waves/block).
// Last block to finish (device-scope done-counter) finalizes the scalars.
// Verified correct in round 3 (absmax 0.0039).
__global__ __launch_bounds__(1024)
void epilogue_kernel(float* __restrict__ out) {
  const int tid  = threadIdx.x;
  const int lane = tid & 63;
  const int w    = tid >> 6;    // 0..15
  const int t    = blockIdx.x * 16 + w;

  float* out_rw  = out;                        // [16384][2]
  float* out_idx = out + 2 * TOKENS;           // [16384][2]
  float* out_rp  = out + 4 * TOKENS + 1;       // [16384][64]

  // combine split-K partials (16 independent loads, latency hidden by occupancy)
  float cl = 0.0f, nl = 0.0f;
  #pragma unroll
  for (int s = 0; s < KSPLIT; ++s) {
    cl += g_part[s][t][lane];
    nl += g_part[s][t][NEXP + lane];
  }

  // router_probs = softmax(clean)
  const float m  = wave_max64(cl);
  const float v  = expf(cl - m);
  const float Z  = wave_sum64(v);
  const float rp = v / Z;
  out_rp[(size_t)t * NEXP + lane] = rp;

  // noisy logits
  const float ns  = softplus_ref(nl);
  const float noi = noise_normal((uint32_t)(t * NEXP + lane));
  const float lgn = __fadd_rn(cl, __fmul_rn(noi, ns));

  const float m2 = wave_max64(lgn);
  const float v2 = expf(lgn - m2);
  const float Z2 = wave_sum64(v2);
  const float p  = v2 / Z2;

  float p1; int i1;
  wave_argmax64(p, lane, p1, i1);
  const float pm = (lane == i1) ? -3.402823466e38f : p;
  float p2; int i2;
  wave_argmax64(pm, lane, p2, i2);

  const float c_acc = (float)((lane == i1) + (lane == i2));

  if (lane == 0) {
    const float s = p1 + p2;
    out_rw[t * 2 + 0]  = p1 / s;
    out_rw[t * 2 + 1]  = p2 / s;
    out_idx[t * 2 + 0] = (float)i1;
    out_idx[t * 2 + 1] = (float)i2;
  }

  // block-level reduce, then one atomicAdd set per block
  __shared__ float lps[16][NEXP];
  __shared__ float lcb[16][NEXP];
  __shared__ float lspw[16];
  lps[w][lane] = rp;
  lcb[w][lane] = c_acc;
  const float spw = wave_sum64(ns);
  if (lane == 0) lspw[w] = spw;
  __syncthreads();
  if (tid < NEXP) {
    float a = 0.0f, b = 0.0f;
    #pragma unroll
    for (int j = 0; j < 16; ++j) { a += lps[j][tid]; b += lcb[j][tid]; }
    atomicAdd(&g_ps[tid],  a);
    atomicAdd(&g_cnt[tid], b);
  }
  if (tid == 0) {
    float s = 0.0f;
    #pragma unroll
    for (int j = 0; j < 16; ++j) s += lspw[j];
    atomicAdd(&g_spa[0], s);
  }

  // ---- last-done block finalizes scalars ----
  __syncthreads();             // all this block's atomics issued & drained
  __shared__ int s_last;
  if (tid == 0) {
    __threadfence();           // release our accumulator adds device-wide
    const unsigned prev = __hip_atomic_fetch_add(&g_done, 1u, __ATOMIC_ACQ_REL,
                                                 __HIP_MEMORY_SCOPE_AGENT);
    s_last = (prev == (unsigned)(gridDim.x - 1)) ? 1 : 0;
  }
  __syncthreads();
  if (s_last && tid < NEXP) {
    __threadfence();           // acquire side
    const float cnt = __hip_atomic_load(&g_cnt[tid], __ATOMIC_RELAXED, __HIP_MEMORY_SCOPE_AGENT);
    const float ps  = __hip_atomic_load(&g_ps[tid],  __ATOMIC_RELAXED, __HIP_MEMORY_SCOPE_AGENT);
    float term = (cnt / (float)TOKENS) * (ps / (float)TOKENS);
    #pragma unroll
    for (int off = 32; off; off >>= 1) term += __shfl_xor(term, off, 64);
    if (tid == 0) {
      out[4 * TOKENS] = 0.64f * term;   // LOAD_BALANCE_WEIGHT * NUM_EXPERTS
      const float spa = __hip_atomic_load(&g_spa[0], __ATOMIC_RELAXED, __HIP_MEMORY_SCOPE_AGENT);
      out[4 * TOKENS + 1 + TOKENS * NEXP] = spa / (float)(TOKENS * NEXP);
      __hip_atomic_store(&g_done, 0u, __ATOMIC_RELAXED, __HIP_MEMORY_SCOPE_AGENT);
    }
  }
}

// ---------------- host ----------------
extern "C" void kernel_launch(void* const* d_in, const int* in_sizes, int n_in,
                              void* d_out, int out_size, void* d_ws, size_t ws_size,
                              hipStream_t stream) {
  const float* x  = (const float*)d_in[0];   // f32 [4,4096,1024]
  const float* wg = (const float*)d_in[1];   // f32 [64,1024]
  const float* wn = (const float*)d_in[2];   // f32 [64,1024]
  float* out = (float*)d_out;                // f32, 1114114 elements

  (void)d_ws; (void)ws_size; (void)in_sizes; (void)n_in; (void)out_size;

  NoisyTopKRouter_57621281243491_kernel<<<dim3(NTT, KSPLIT), 256, 0, stream>>>(x, wg, wn);
  epilogue_kernel<<<TOKENS / 16, 1024, 0, stream>>>(out);
}

// Round 5
// 173.007 us; speedup vs baseline: 2.6341x; 1.3475x over previous
//
#include <hip/hip_runtime.h>
#include <stdint.h>

#define TOKENS 16384
#define DDIM   1024
#define NEXP   64
#define NCOL   128              // 64 gate + 64 noise cols
#define TB     32               // tokens per block
#define NBLK   (TOKENS / TB)    // 512 blocks
#define NCH    (DDIM / 32)      // 32 k-chunks of 32

typedef __attribute__((ext_vector_type(8))) short bf16x8;  // 8 bf16 = 4 VGPR
typedef __attribute__((ext_vector_type(4))) float f32x4;

// -------- device-global scratch --------
__device__ ushort g_wh[NCOL][DDIM];   // W split: high bf16
__device__ ushort g_wm[NCOL][DDIM];   // mid
__device__ ushort g_wl[NCOL][DDIM];   // low
__device__ float g_ps[NEXP];          // sum of clean router probs per expert
__device__ float g_cnt[NEXP];         // top-2 counts per expert
__device__ float g_spa[1];            // sum of softplus

// ---------------- bf16 3-way split (x = h + m + l + O(2^-27 x)) ----------------
__device__ inline ushort bf16rne(float f) {
  uint32_t u = __float_as_uint(f);
  return (ushort)((u + 0x7fffu + ((u >> 16) & 1u)) >> 16);
}
__device__ inline float bf16tof(ushort h) {
  return __uint_as_float(((uint32_t)h) << 16);
}
__device__ inline void split3(float v, ushort& h, ushort& m, ushort& l) {
  h = bf16rne(v);
  float r1 = v - bf16tof(h);     // exact (Sterbenz-style cancellation)
  m = bf16rne(r1);
  float r2 = r1 - bf16tof(m);    // exact
  l = bf16rne(r2);
}

// ---------------- JAX threefry2x32 (20 rounds) ----------------
struct U2 { uint32_t a, b; };

__host__ __device__ constexpr U2 tf2x32(uint32_t k0, uint32_t k1,
                                        uint32_t x0, uint32_t x1) {
  uint32_t ks[3] = {k0, k1, k0 ^ k1 ^ 0x1BD11BDAu};
  const uint32_t rot[2][4] = {{13u, 15u, 26u, 6u}, {17u, 29u, 16u, 24u}};
  x0 += ks[0]; x1 += ks[1];
  for (int d = 0; d < 5; ++d) {
    for (int j = 0; j < 4; ++j) {
      uint32_t r = rot[d & 1][j];
      x0 += x1;
      x1 = (x1 << r) | (x1 >> (32u - r));
      x1 ^= x0;
    }
    x0 += ks[(d + 1) % 3];
    x1 += ks[(d + 2) % 3] + (uint32_t)(d + 1);
  }
  return U2{x0, x1};
}

// JAX >=0.5 partitionable threefry: bits[i] = xor-fold(tf(key, (0, i)))
__device__ inline uint32_t noise_bits(uint32_t i) {
  constexpr U2 NK = tf2x32(0u, 0u, 0u, 12345u);   // fold_in(key(0), 12345)
  U2 o = tf2x32(NK.a, NK.b, 0u, i);
  return o.a ^ o.b;
}

// XLA ErfInv32 (Giles polynomial)
__device__ inline float xla_erfinv(float x) {
  float w = -log1pf(-x * x);
  float p;
  if (w < 5.0f) {
    w = w - 2.5f;
    p = 2.81022636e-08f;
    p = 3.43273939e-07f + p * w;
    p = -3.5233877e-06f + p * w;
    p = -4.39150654e-06f + p * w;
    p = 0.00021858087f + p * w;
    p = -0.00125372503f + p * w;
    p = -0.00417768164f + p * w;
    p = 0.246640727f + p * w;
    p = 1.50140941f + p * w;
  } else {
    w = sqrtf(w) - 3.0f;
    p = -0.000200214257f;
    p = 0.000100950558f + p * w;
    p = 0.00134934322f + p * w;
    p = -0.00367342844f + p * w;
    p = 0.00573950773f + p * w;
    p = -0.0076224613f + p * w;
    p = 0.00943887047f + p * w;
    p = 1.00167406f + p * w;
    p = 2.83297682f + p * w;
  }
  return p * x;
}

__device__ inline float noise_normal(uint32_t i) {
  uint32_t bits = noise_bits(i);
  float f = __uint_as_float((bits >> 9) | 0x3f800000u) - 1.0f;  // [0,1)
  float u = f * 2.0f + (-0.99999994f);
  u = fmaxf(u, -0.99999994f);
  return 1.41421356237f * xla_erfinv(u);
}

__device__ inline float softplus_ref(float x) {
  return fmaxf(x, 0.0f) + log1pf(expf(-fabsf(x)));
}

// ---------------- wave(64) primitives ----------------
__device__ inline float wave_max64(float v) {
  #pragma unroll
  for (int off = 32; off; off >>= 1) v = fmaxf(v, __shfl_xor(v, off, 64));
  return v;
}
__device__ inline float wave_sum64(float v) {
  #pragma unroll
  for (int off = 32; off; off >>= 1) v += __shfl_xor(v, off, 64);
  return v;
}
__device__ inline void wave_argmax64(float v, int idx, float& mv, int& mi) {
  float bv = v; int bi = idx;
  #pragma unroll
  for (int off = 32; off; off >>= 1) {
    float ov = __shfl_xor(bv, off, 64);
    int   oi = __shfl_xor(bi, off, 64);
    if (ov > bv || (ov == bv && oi < bi)) { bv = ov; bi = oi; }
  }
  mv = bv; mi = bi;
}

// XOR swizzle: place k-oct `slot` of row `row` at slot (slot ^ f(row)).
// Spreads the 16 rows of a frag-read over 8 bank-quads (2-way = free).
__device__ __forceinline__ int wswz(int row, int slot) {
  return row * 32 + ((slot ^ ((row ^ (row >> 2)) & 3)) << 3);
}

// ---------------- K0: split W into bf16 h/m/l, zero accumulators ----------------
__global__ __launch_bounds__(256)
void wsplit_kernel(const float* __restrict__ wg, const float* __restrict__ wn) {
  const int col = blockIdx.x;            // 0..127
  const int tid = threadIdx.x;           // 0..255, 4 k each
  const float* src = (col < NEXP) ? (wg + (size_t)col * DDIM)
                                  : (wn + (size_t)(col - NEXP) * DDIM);
  float4 v = *(const float4*)&src[tid * 4];
  ushort h[4], m[4], l[4];
  split3(v.x, h[0], m[0], l[0]);
  split3(v.y, h[1], m[1], l[1]);
  split3(v.z, h[2], m[2], l[2]);
  split3(v.w, h[3], m[3], l[3]);
  *(ushort4*)&g_wh[col][tid * 4] = make_ushort4(h[0], h[1], h[2], h[3]);
  *(ushort4*)&g_wm[col][tid * 4] = make_ushort4(m[0], m[1], m[2], m[3]);
  *(ushort4*)&g_wl[col][tid * 4] = make_ushort4(l[0], l[1], l[2], l[3]);

  if (col == 0) {   // zero loss accumulators (K0->K1 kernel boundary orders)
    if (tid < NEXP) { g_ps[tid] = 0.0f; g_cnt[tid] = 0.0f; }
    if (tid == NEXP) g_spa[0] = 0.0f;
  }
}

// ---------------- K1: fused split-bf16 MFMA GEMM + router epilogue ----------------
// block = 512 threads (8 waves) = 32 tokens x 128 cols x full K.
// waves: tg = w>>2 (16-token group), cg = w&3 (32-col group); each wave owns
// a 16x32 output tile = 2 MFMA col-tiles, acc 8 VGPR.
// Per k-chunk (32 k): stage x (fp32->3xbf16 on the fly) and W (pre-split) into
// swizzled LDS, then 2 col-tiles x 6 split-products of mfma_f32_16x16x32_bf16.
// Logits land in LDS; epilogue (verified r1 math) runs in-block. No g_part.
__global__ __launch_bounds__(512, 4)
void NoisyTopKRouter_57621281243491_kernel(
    const float* __restrict__ x, float* __restrict__ out) {
  __shared__ short lds_w[3][NCOL * 32];        // 3 x 8 KB
  __shared__ short lds_x[3][TB * 32];          // 3 x 2 KB
  __shared__ float lds_logits[TB][NCOL + 4];   // 16.5 KB
  __shared__ float lps[8][NEXP];
  __shared__ float lcb[8][NEXP];
  __shared__ float lspw[8];

  const int tid  = threadIdx.x;
  const int w    = tid >> 6;          // wave 0..7
  const int lane = tid & 63;
  const int tg   = w >> 2;            // token group 0..1
  const int cg   = w & 3;             // col group 0..3
  const int tok0 = blockIdx.x * TB;

  // staging roles
  const int sw_col = tid >> 2;        // 0..127: W col
  const int sw_slot = tid & 3;        // k-oct 0..3
  const int sx_tok = tid >> 4;        // 0..31: x token
  const int sx_kp  = tid & 15;        // k-pair 0..15

  const float* xrow = x + (size_t)(tok0 + sx_tok) * DDIM + sx_kp * 2;
  const int wWidx = wswz(sw_col, sw_slot);                 // W LDS write idx
  const int xWidx = (sx_tok * 32 + sx_kp * 2)
                    ^ (((sx_tok ^ (sx_tok >> 2)) & 3) << 3);  // x LDS write idx (u32 grain)

  // frag-read roles: lane l -> row l&15, k-oct l>>4 (same gather for A and B;
  // any hw k-permutation cancels since both operands use the identical map)
  const int fr_row = lane & 15;
  const int fr_s   = lane >> 4;
  const int fAidx  = wswz(tg * 16 + fr_row, fr_s);
  const int fB0idx = wswz(cg * 32 + fr_row, fr_s);
  const int fB1idx = wswz(cg * 32 + 16 + fr_row, fr_s);

  f32x4 acc0 = {0.f, 0.f, 0.f, 0.f};
  f32x4 acc1 = {0.f, 0.f, 0.f, 0.f};

  for (int kc = 0; kc < NCH; ++kc) {
    const int kbase = kc * 32;

    // issue global loads early (latency overlaps the barrier wait)
    const float2 xv = *(const float2*)&xrow[kbase];
    const bf16x8 wh = *(const bf16x8*)&g_wh[sw_col][kbase + sw_slot * 8];
    const bf16x8 wm = *(const bf16x8*)&g_wm[sw_col][kbase + sw_slot * 8];
    const bf16x8 wl = *(const bf16x8*)&g_wl[sw_col][kbase + sw_slot * 8];

    if (kc) __syncthreads();          // previous chunk's frag reads done

    ushort h0, m0, l0, h1, m1, l1;
    split3(xv.x, h0, m0, l0);
    split3(xv.y, h1, m1, l1);
    ((uint*)lds_x[0])[xWidx >> 1] = (uint)(ushort)h0 | ((uint)(ushort)h1 << 16);
    ((uint*)lds_x[1])[xWidx >> 1] = (uint)(ushort)m0 | ((uint)(ushort)m1 << 16);
    ((uint*)lds_x[2])[xWidx >> 1] = (uint)(ushort)l0 | ((uint)(ushort)l1 << 16);
    *(bf16x8*)&lds_w[0][wWidx] = wh;
    *(bf16x8*)&lds_w[1][wWidx] = wm;
    *(bf16x8*)&lds_w[2][wWidx] = wl;
    __syncthreads();

    const bf16x8 Ah = *(const bf16x8*)&lds_x[0][fAidx];
    const bf16x8 Am = *(const bf16x8*)&lds_x[1][fAidx];
    const bf16x8 Al = *(const bf16x8*)&lds_x[2][fAidx];

    {
      const bf16x8 Bh = *(const bf16x8*)&lds_w[0][fB0idx];
      const bf16x8 Bm = *(const bf16x8*)&lds_w[1][fB0idx];
      const bf16x8 Bl = *(const bf16x8*)&lds_w[2][fB0idx];
      acc0 = __builtin_amdgcn_mfma_f32_16x16x32_bf16(Ah, Bh, acc0, 0, 0, 0);
      acc0 = __builtin_amdgcn_mfma_f32_16x16x32_bf16(Ah, Bm, acc0, 0, 0, 0);
      acc0 = __builtin_amdgcn_mfma_f32_16x16x32_bf16(Am, Bh, acc0, 0, 0, 0);
      acc0 = __builtin_amdgcn_mfma_f32_16x16x32_bf16(Ah, Bl, acc0, 0, 0, 0);
      acc0 = __builtin_amdgcn_mfma_f32_16x16x32_bf16(Al, Bh, acc0, 0, 0, 0);
      acc0 = __builtin_amdgcn_mfma_f32_16x16x32_bf16(Am, Bm, acc0, 0, 0, 0);
    }
    {
      const bf16x8 Bh = *(const bf16x8*)&lds_w[0][fB1idx];
      const bf16x8 Bm = *(const bf16x8*)&lds_w[1][fB1idx];
      const bf16x8 Bl = *(const bf16x8*)&lds_w[2][fB1idx];
      acc1 = __builtin_amdgcn_mfma_f32_16x16x32_bf16(Ah, Bh, acc1, 0, 0, 0);
      acc1 = __builtin_amdgcn_mfma_f32_16x16x32_bf16(Ah, Bm, acc1, 0, 0, 0);
      acc1 = __builtin_amdgcn_mfma_f32_16x16x32_bf16(Am, Bh, acc1, 0, 0, 0);
      acc1 = __builtin_amdgcn_mfma_f32_16x16x32_bf16(Ah, Bl, acc1, 0, 0, 0);
      acc1 = __builtin_amdgcn_mfma_f32_16x16x32_bf16(Al, Bh, acc1, 0, 0, 0);
      acc1 = __builtin_amdgcn_mfma_f32_16x16x32_bf16(Am, Bm, acc1, 0, 0, 0);
    }
  }

  // C-write to LDS logits: D row = 4*(lane>>4)+reg, col = lane&15 (m89-verified)
  #pragma unroll
  for (int r = 0; r < 4; ++r) {
    lds_logits[tg * 16 + 4 * fr_s + r][cg * 32 + fr_row]      = acc0[r];
    lds_logits[tg * 16 + 4 * fr_s + r][cg * 32 + 16 + fr_row] = acc1[r];
  }
  __syncthreads();

  // ---- epilogue: 4 tokens per wave, lane = expert (identical to r1 K2 math) ----
  float* out_rw  = out;                        // [16384][2]
  float* out_idx = out + 2 * TOKENS;           // [16384][2]
  float* out_rp  = out + 4 * TOKENS + 1;       // [16384][64]

  float ps_acc = 0.0f, sp_acc = 0.0f, c_acc = 0.0f;

  for (int it = 0; it < 4; ++it) {
    const int tl = w * 4 + it;
    const int t  = tok0 + tl;
    const float cl = lds_logits[tl][lane];
    const float nl = lds_logits[tl][NEXP + lane];

    // router_probs = softmax(clean)
    const float m  = wave_max64(cl);
    const float v  = expf(cl - m);
    const float Z  = wave_sum64(v);
    const float rp = v / Z;
    out_rp[(size_t)t * NEXP + lane] = rp;
    ps_acc += rp;

    // noisy logits
    const float ns  = softplus_ref(nl);
    sp_acc += ns;
    const float noi = noise_normal((uint32_t)(t * NEXP + lane));
    const float lgn = __fadd_rn(cl, __fmul_rn(noi, ns));

    const float m2 = wave_max64(lgn);
    const float v2 = expf(lgn - m2);
    const float Z2 = wave_sum64(v2);
    const float p  = v2 / Z2;

    float p1; int i1;
    wave_argmax64(p, lane, p1, i1);
    const float pm = (lane == i1) ? -3.402823466e38f : p;
    float p2; int i2;
    wave_argmax64(pm, lane, p2, i2);

    c_acc += (float)((lane == i1) + (lane == i2));

    if (lane == 0) {
      const float s = p1 + p2;
      out_rw[t * 2 + 0]  = p1 / s;
      out_rw[t * 2 + 1]  = p2 / s;
      out_idx[t * 2 + 0] = (float)i1;
      out_idx[t * 2 + 1] = (float)i2;
    }
  }

  // block-level reduce, then one atomicAdd set per block
  lps[w][lane] = ps_acc;
  lcb[w][lane] = c_acc;
  const float spw = wave_sum64(sp_acc);
  if (lane == 0) lspw[w] = spw;
  __syncthreads();
  if (tid < NEXP) {
    float a = 0.0f, b = 0.0f;
    #pragma unroll
    for (int j = 0; j < 8; ++j) { a += lps[j][tid]; b += lcb[j][tid]; }
    atomicAdd(&g_ps[tid],  a);
    atomicAdd(&g_cnt[tid], b);
  }
  if (tid == 0) {
    float s = 0.0f;
    #pragma unroll
    for (int j = 0; j < 8; ++j) s += lspw[j];
    atomicAdd(&g_spa[0], s);
  }
}

// ---------------- K3: finalize scalars ----------------
__global__ void finalize_kernel(float* __restrict__ out) {
  const int lane = threadIdx.x;
  float term = (g_cnt[lane] / (float)TOKENS) * (g_ps[lane] / (float)TOKENS);
  #pragma unroll
  for (int off = 32; off; off >>= 1) term += __shfl_xor(term, off, 64);
  if (lane == 0) {
    out[4 * TOKENS] = 0.64f * term;   // LOAD_BALANCE_WEIGHT * NUM_EXPERTS
    out[4 * TOKENS + 1 + TOKENS * NEXP] = g_spa[0] / (float)(TOKENS * NEXP);
  }
}

// ---------------- host ----------------
extern "C" void kernel_launch(void* const* d_in, const int* in_sizes, int n_in,
                              void* d_out, int out_size, void* d_ws, size_t ws_size,
                              hipStream_t stream) {
  const float* x  = (const float*)d_in[0];   // f32 [4,4096,1024]
  const float* wg = (const float*)d_in[1];   // f32 [64,1024]
  const float* wn = (const float*)d_in[2];   // f32 [64,1024]
  float* out = (float*)d_out;                // f32, 1114114 elements

  (void)d_ws; (void)ws_size; (void)in_sizes; (void)n_in; (void)out_size;

  wsplit_kernel<<<NCOL, 256, 0, stream>>>(wg, wn);
  NoisyTopKRouter_57621281243491_kernel<<<NBLK, 512, 0, stream>>>(x, out);
  finalize_kernel<<<1, 64, 0, stream>>>(out);
}